// Round 4
// baseline (1269.248 us; speedup 1.0000x reference)
//
#include <hip/hip_runtime.h>

#define L_SEQ 1024
#define NB 32
#define NH 8
#define NE 64
#define TOPK 6
#define PI_F 3.14159265358979323846f
#define RS 1089   // LDS row stride: 1024 + 64 (pad every 16) + 1 (odd stride for bank spread)

// physical offset of point p within a padded LDS row: contiguous 16-groups at stride 17
__device__ __forceinline__ int physp(int p) { return 17 * (p >> 4) + (p & 15); }

// ---------------- register-resident complex-1024 FFT (per wave) ----------------
// layout: point p = 16*lane + r ; lane = 0..63, r = 0..15
// forward: radix-2 DIF, natural input -> bit-reversed output
// inverse: radix-2 DIT, bit-reversed input -> natural output (scale 1/N applied by caller)
// NOTE: single-array stages only. The paired (q,k) variant kept 64 data floats
// + hoisted shfl results live -> structural spill at any reasonable VGPR cap
// (rounds 2-3: 1.2 GB scratch writes). Q.re parks in LDS between the two FFTs.

template<int DL>
__device__ __forceinline__ void dif_stage(float (&xr)[16], float (&xi)[16],
                                          int lane, float wmr, float wmi)
{
    const bool up = (lane & DL) != 0;
    const float sgn = up ? -1.f : 1.f;
    float bs, bc;
    __sincosf((-PI_F / (float)DL) * (float)(lane & (DL - 1)), &bs, &bc);
    float twr = bc, twi = bs;   // W_M^{16*(lane mod DL)}
#pragma unroll
    for (int r = 0; r < 16; ++r) {
        const float pr = __shfl_xor(xr[r], DL, 64);
        const float pi = __shfl_xor(xi[r], DL, 64);
        const float tr = fmaf(sgn, xr[r], pr);   // clear: a+b ; up: a-b
        const float ti = fmaf(sgn, xi[r], pi);
        const float mr = tr * twr - ti * twi;
        const float mi = tr * twi + ti * twr;
        xr[r] = up ? mr : tr;
        xi[r] = up ? mi : ti;
        const float nr = twr * wmr - twi * wmi;   // advance by W_M
        const float ni = twr * wmi + twi * wmr;
        twr = nr; twi = ni;
    }
}

// inverse cross-lane DIT stage, conjugate twiddles (wmi positive)
template<int DL>
__device__ __forceinline__ void dit_stage(float (&xr)[16], float (&xi)[16],
                                          int lane, float wmr, float wmi)
{
    const bool up = (lane & DL) != 0;
    const float sgn = up ? -1.f : 1.f;
    float bs, bc;
    __sincosf((PI_F / (float)DL) * (float)(lane & (DL - 1)), &bs, &bc);
    float twr = bc, twi = bs;
#pragma unroll
    for (int r = 0; r < 16; ++r) {
        const float pr  = __shfl_xor(xr[r], DL, 64);
        const float pim = __shfl_xor(xi[r], DL, 64);
        const float vr = up ? xr[r] : pr;    // the 'b' operand (gets twiddled)
        const float vi = up ? xi[r] : pim;
        const float ur = up ? pr : xr[r];    // the 'a' operand
        const float ui = up ? pim : xi[r];
        const float cr_ = vr * twr - vi * twi;
        const float ci_ = vr * twi + vi * twr;
        xr[r] = fmaf(sgn, cr_, ur);          // clear: a + tw*b ; up: a - tw*b
        xi[r] = fmaf(sgn, ci_, ui);
        const float nr = twr * wmr - twi * wmi;
        const float ni = twr * wmi + twi * wmr;
        twr = nr; twi = ni;
    }
}

// forward in-register stages: M = 16, 8, 4, 2 (twiddles are compile-time constants)
__device__ __forceinline__ void fft_inreg_fwd(float (&xr)[16], float (&xi)[16])
{
    const float R16[8] = {1.f, 0.92387953f, 0.70710678f, 0.38268343f, 0.f, -0.38268343f, -0.70710678f, -0.92387953f};
    const float I16[8] = {0.f, -0.38268343f, -0.70710678f, -0.92387953f, -1.f, -0.92387953f, -0.70710678f, -0.38268343f};
#pragma unroll
    for (int j = 0; j < 8; ++j) {
        const float ar = xr[j], ai = xi[j], br = xr[j + 8], bi = xi[j + 8];
        const float dr = ar - br, di = ai - bi;
        xr[j] = ar + br; xi[j] = ai + bi;
        xr[j + 8] = dr * R16[j] - di * I16[j];
        xi[j + 8] = dr * I16[j] + di * R16[j];
    }
    const float R8[4] = {1.f, 0.70710678f, 0.f, -0.70710678f};
    const float I8[4] = {0.f, -0.70710678f, -1.f, -0.70710678f};
#pragma unroll
    for (int b = 0; b < 16; b += 8) {
#pragma unroll
        for (int j = 0; j < 4; ++j) {
            const int i0 = b + j, i1 = i0 + 4;
            const float ar = xr[i0], ai = xi[i0], br = xr[i1], bi = xi[i1];
            const float dr = ar - br, di = ai - bi;
            xr[i0] = ar + br; xi[i0] = ai + bi;
            xr[i1] = dr * R8[j] - di * I8[j];
            xi[i1] = dr * I8[j] + di * R8[j];
        }
    }
#pragma unroll
    for (int b = 0; b < 16; b += 4) {
        {
            const float ar = xr[b], ai = xi[b], br = xr[b + 2], bi = xi[b + 2];
            xr[b] = ar + br; xi[b] = ai + bi;
            xr[b + 2] = ar - br; xi[b + 2] = ai - bi;
        }
        {   // twiddle -i: (d)*( -i ) = (di, -dr)
            const float ar = xr[b + 1], ai = xi[b + 1], br = xr[b + 3], bi = xi[b + 3];
            const float dr = ar - br, di = ai - bi;
            xr[b + 1] = ar + br; xi[b + 1] = ai + bi;
            xr[b + 3] = di; xi[b + 3] = -dr;
        }
    }
#pragma unroll
    for (int b = 0; b < 16; b += 2) {
        const float ar = xr[b], ai = xi[b], br = xr[b + 1], bi = xi[b + 1];
        xr[b] = ar + br; xi[b] = ai + bi;
        xr[b + 1] = ar - br; xi[b + 1] = ai - bi;
    }
}

// inverse in-register stages: M = 2, 4, 8, 16 (DIT form, conjugate twiddles)
__device__ __forceinline__ void fft_inreg_inv(float (&xr)[16], float (&xi)[16])
{
#pragma unroll
    for (int b = 0; b < 16; b += 2) {
        const float ar = xr[b], ai = xi[b], br = xr[b + 1], bi = xi[b + 1];
        xr[b] = ar + br; xi[b] = ai + bi;
        xr[b + 1] = ar - br; xi[b + 1] = ai - bi;
    }
#pragma unroll
    for (int b = 0; b < 16; b += 4) {
        {
            const float ar = xr[b], ai = xi[b], tr = xr[b + 2], ti = xi[b + 2];
            xr[b] = ar + tr; xi[b] = ai + ti;
            xr[b + 2] = ar - tr; xi[b + 2] = ai - ti;
        }
        {   // twiddle +i: t = i*b = (-bi, br)
            const float ar = xr[b + 1], ai = xi[b + 1], br = xr[b + 3], bi = xi[b + 3];
            const float tr = -bi, ti = br;
            xr[b + 1] = ar + tr; xi[b + 1] = ai + ti;
            xr[b + 3] = ar - tr; xi[b + 3] = ai - ti;
        }
    }
    const float R8[4] = {1.f, 0.70710678f, 0.f, -0.70710678f};
    const float I8[4] = {0.f, 0.70710678f, 1.f, 0.70710678f};
#pragma unroll
    for (int b = 0; b < 16; b += 8) {
#pragma unroll
        for (int j = 0; j < 4; ++j) {
            const int i0 = b + j, i1 = i0 + 4;
            const float br = xr[i1], bi = xi[i1];
            const float tr = br * R8[j] - bi * I8[j];
            const float ti = br * I8[j] + bi * R8[j];
            const float ar = xr[i0], ai = xi[i0];
            xr[i0] = ar + tr; xi[i0] = ai + ti;
            xr[i1] = ar - tr; xi[i1] = ai - ti;
        }
    }
    const float R16[8] = {1.f, 0.92387953f, 0.70710678f, 0.38268343f, 0.f, -0.38268343f, -0.70710678f, -0.92387953f};
    const float I16[8] = {0.f, 0.38268343f, 0.70710678f, 0.92387953f, 1.f, 0.92387953f, 0.70710678f, 0.38268343f};
#pragma unroll
    for (int j = 0; j < 8; ++j) {
        const int i0 = j, i1 = j + 8;
        const float br = xr[i1], bi = xi[i1];
        const float tr = br * R16[j] - bi * I16[j];
        const float ti = br * I16[j] + bi * R16[j];
        const float ar = xr[i0], ai = xi[i0];
        xr[i0] = ar + tr; xi[i0] = ai + ti;
        xr[i1] = ar - tr; xi[i1] = ai - ti;
    }
}

__device__ __forceinline__ void fft1024_fwd(float (&xr)[16], float (&xi)[16], int lane)
{
    dif_stage<32>(xr, xi, lane, 0.99998117f, -0.00613588f);  // M=1024
    dif_stage<16>(xr, xi, lane, 0.99992470f, -0.01227154f);  // M=512
    dif_stage<8>(xr, xi, lane, 0.99969882f, -0.02454123f);   // M=256
    dif_stage<4>(xr, xi, lane, 0.99879546f, -0.04906767f);   // M=128
    dif_stage<2>(xr, xi, lane, 0.99518473f, -0.09801714f);   // M=64
    dif_stage<1>(xr, xi, lane, 0.98078528f, -0.19509032f);   // M=32
    fft_inreg_fwd(xr, xi);
}

__device__ __forceinline__ void fft1024_inv(float (&xr)[16], float (&xi)[16], int lane)
{
    fft_inreg_inv(xr, xi);
    dit_stage<1>(xr, xi, lane, 0.98078528f, 0.19509032f);    // M=32
    dit_stage<2>(xr, xi, lane, 0.99518473f, 0.09801714f);    // M=64
    dit_stage<4>(xr, xi, lane, 0.99879546f, 0.04906767f);    // M=128
    dit_stage<8>(xr, xi, lane, 0.99969882f, 0.02454123f);    // M=256
    dit_stage<16>(xr, xi, lane, 0.99992470f, 0.01227154f);   // M=512
    dit_stage<32>(xr, xi, lane, 0.99998117f, 0.00613588f);   // M=1024
}

// ---------------- Kernel A: FFT autocorrelation ----------------
// grid: (E/16, H, N), block = 512 (8 waves); each block: 16 series of (n,h)
__global__ __launch_bounds__(512, 1) void fftcorr_kernel(
    const float* __restrict__ q, const float* __restrict__ k,
    float* __restrict__ corr_out, float* __restrict__ ws_mean)
{
    extern __shared__ float lds[];
    float* lq = lds;
    float* lk = lds + 16 * RS;

    const int tid = threadIdx.x;
    const int n = blockIdx.z, h = blockIdx.y, e0 = blockIdx.x * 16;

    // ---- stage q,k: float4 loads (64B coalesced), scalar LDS writes into padded rows
    {
        const int eq = tid & 3;       // which float4 of the 16 e's
        const int trow = tid >> 2;    // 0..127
#pragma unroll
        for (int c = 0; c < 8; ++c) {
            const int t = c * 128 + trow;
            const size_t gbase = ((((size_t)n * L_SEQ + t) * NH + h) * NE) + e0 + 4 * eq;
            const float4 qv = *reinterpret_cast<const float4*>(q + gbase);
            const float4 kv = *reinterpret_cast<const float4*>(k + gbase);
            const int ph = physp(t);
            lq[(4 * eq + 0) * RS + ph] = qv.x;
            lq[(4 * eq + 1) * RS + ph] = qv.y;
            lq[(4 * eq + 2) * RS + ph] = qv.z;
            lq[(4 * eq + 3) * RS + ph] = qv.w;
            lk[(4 * eq + 0) * RS + ph] = kv.x;
            lk[(4 * eq + 1) * RS + ph] = kv.y;
            lk[(4 * eq + 2) * RS + ph] = kv.z;
            lk[(4 * eq + 3) * RS + ph] = kv.w;
        }
    }
    __syncthreads();

    const int lane = tid & 63;
    const int wv = tid >> 6;          // 0..7

#pragma unroll 1
    for (int s = 0; s < 2; ++s) {
        const int e = 2 * wv + s;
        const int row = e * RS + 17 * lane;   // physp(16*lane + r) = 17*lane + r
        float ar[16], ai[16];

        // ---- Q forward FFT (32 data floats live)
#pragma unroll
        for (int r = 0; r < 16; ++r) { ar[r] = lq[row + r]; ai[r] = 0.f; }
        fft1024_fwd(ar, ai, lane);

        // park Q.re in the (dead) q LDS row; keep Q.im in regs
        float qi[16];
#pragma unroll
        for (int r = 0; r < 16; ++r) { lq[row + r] = ar[r]; qi[r] = ai[r]; }

        // ---- K forward FFT (peak live: 32 + 16 parked-im + temps)
#pragma unroll
        for (int r = 0; r < 16; ++r) { ar[r] = lk[row + r]; ai[r] = 0.f; }
        fft1024_fwd(ar, ai, lane);

        // ---- S = Q * conj(K) / 1024  (elementwise in bit-reversed order)
#pragma unroll
        for (int r = 0; r < 16; ++r) {
            const float qr = lq[row + r];         // per-lane own slots, conflict-free
            const float sr = qr * ar[r] + qi[r] * ai[r];
            const float si = qi[r] * ar[r] - qr * ai[r];
            ar[r] = sr * (1.f / 1024.f);
            ai[r] = si * (1.f / 1024.f);
        }

        fft1024_inv(ar, ai, lane);            // corr (natural order, real)

#pragma unroll
        for (int r = 0; r < 16; ++r) lq[row + r] = ar[r];
    }
    __syncthreads();

    // ---- transposed coalesced writeout + per-l mean partials
    {
        const int j = tid & 15;       // e within tile
        const int lr = tid >> 4;      // 0..31
#pragma unroll 1
        for (int c = 0; c < 32; ++c) {
            const int l = c * 32 + lr;
            const float val = lq[j * RS + physp(l)];
            corr_out[((((size_t)n * L_SEQ + l) * NH + h) * NE) + e0 + j] = val;
            float sum = val;
            sum += __shfl_xor(sum, 1, 64);
            sum += __shfl_xor(sum, 2, 64);
            sum += __shfl_xor(sum, 4, 64);
            sum += __shfl_xor(sum, 8, 64);
            if (j == 0) atomicAdd(&ws_mean[n * L_SEQ + l], sum);
        }
    }
}

// ---------------- Kernel B: top-6 lags + per-n softmax ----------------
__global__ __launch_bounds__(1024) void topk_softmax_kernel(
    const float* __restrict__ ws_mean, int* __restrict__ ws_idx,
    float* __restrict__ ws_w)
{
    __shared__ float val[1024];
    __shared__ float rv[1024];
    __shared__ int   ri[1024];
    __shared__ int   sel[TOPK];
    const int tid = threadIdx.x;

    float s = 0.f;
    for (int n = 0; n < NB; ++n) s += ws_mean[n * L_SEQ + tid];
    val[tid] = s;
    __syncthreads();

    for (int kk = 0; kk < TOPK; ++kk) {
        rv[tid] = val[tid];
        ri[tid] = tid;
        __syncthreads();
        for (int off = 512; off > 0; off >>= 1) {
            if (tid < off) {
                const float a = rv[tid], b = rv[tid + off];
                const int ia = ri[tid], ib = ri[tid + off];
                if (b > a || (b == a && ib < ia)) { rv[tid] = b; ri[tid] = ib; }
            }
            __syncthreads();
        }
        if (tid == 0) { sel[kk] = ri[0]; val[ri[0]] = -1e30f; }
        __syncthreads();
    }
    if (tid < TOPK) ws_idx[tid] = sel[tid];

    if (tid < NB) {
        float wv[TOPK];
        float m = -1e30f;
        for (int kk = 0; kk < TOPK; ++kk) {
            wv[kk] = ws_mean[tid * L_SEQ + sel[kk]] * (1.f / (NH * NE));
            m = fmaxf(m, wv[kk]);
        }
        float sum = 0.f;
        for (int kk = 0; kk < TOPK; ++kk) { wv[kk] = expf(wv[kk] - m); sum += wv[kk]; }
        const float inv = 1.f / sum;
        for (int kk = 0; kk < TOPK; ++kk) ws_w[tid * 8 + kk] = wv[kk] * inv;
    }
}

// ---------------- Kernel C: lag-gather weighted sum of v ----------------
__global__ __launch_bounds__(256) void gather_kernel(
    const float* __restrict__ v, const int* __restrict__ ws_idx,
    const float* __restrict__ ws_w, float* __restrict__ out)
{
    const int n = blockIdx.y;
    const int idx4 = blockIdx.x * 256 + threadIdx.x;
    const int l = idx4 >> 7;
    const int r = idx4 & 127;
    const float* wrow = ws_w + n * 8;

    float4 acc = make_float4(0.f, 0.f, 0.f, 0.f);
#pragma unroll
    for (int kk = 0; kk < TOPK; ++kk) {
        const int t = (l + ws_idx[kk]) & (L_SEQ - 1);
        const float4 vv = *reinterpret_cast<const float4*>(
            v + (((size_t)n * L_SEQ + t) * (NH * NE)) + r * 4);
        const float wk = wrow[kk];
        acc.x = fmaf(wk, vv.x, acc.x);
        acc.y = fmaf(wk, vv.y, acc.y);
        acc.z = fmaf(wk, vv.z, acc.z);
        acc.w = fmaf(wk, vv.w, acc.w);
    }
    *reinterpret_cast<float4*>(out + ((size_t)n * L_SEQ + l) * (NH * NE) + r * 4) = acc;
}

extern "C" void kernel_launch(void* const* d_in, const int* in_sizes, int n_in,
                              void* d_out, int out_size, void* d_ws, size_t ws_size,
                              hipStream_t stream)
{
    const float* q = (const float*)d_in[0];
    const float* k = (const float*)d_in[1];
    const float* v = (const float*)d_in[2];
    float* out = (float*)d_out;
    float* corr_out = out + (size_t)NB * L_SEQ * NH * NE;

    float* ws_mean = (float*)d_ws;                              // 32*1024 f32
    int*   ws_idx  = (int*)((char*)d_ws + 131072);              // 6 ints
    float* ws_w    = (float*)((char*)d_ws + 131072 + 256);      // 32*8 f32

    hipMemsetAsync(d_ws, 0, 131072, stream);
    const size_t lds_bytes = (size_t)2 * 16 * RS * sizeof(float);   // 139,392 B
    fftcorr_kernel<<<dim3(NE / 16, NH, NB), 512, lds_bytes, stream>>>(q, k, corr_out, ws_mean);
    topk_softmax_kernel<<<1, 1024, 0, stream>>>(ws_mean, ws_idx, ws_w);
    gather_kernel<<<dim3(512, NB), 256, 0, stream>>>(v, ws_idx, ws_w, out);
}

// Round 5
// 1055.789 us; speedup vs baseline: 1.2022x; 1.2022x over previous
//
#include <hip/hip_runtime.h>

#define L_SEQ 1024
#define NB 32
#define NH 8
#define NE 64
#define TOPK 6
#define RS 1089   // LDS row stride: 1024 + 64 (pad every 16) + 1 (odd stride for bank spread)

// physical offset of point p within a padded LDS row: contiguous 16-groups at stride 17
__device__ __forceinline__ int physp(int p) { return 17 * (p >> 4) + (p & 15); }

// ---- base-twiddle table: W_64^j = (cos(pi j/32), -sin(pi j/32)), j = 0..31 ----
// Global .rodata (per-lane indexed load, L1-cached). NO runtime sincos anywhere:
// rounds 2-4 showed ~1.1 GB scratch round-trip invariant under data-live-set
// changes -> attributed to sincos call-site spills + serial twiddle recurrence.
__device__ const float TW64C[32] = {
    1.000000000f, 0.995184727f, 0.980785280f, 0.956940336f,
    0.923879533f, 0.881921264f, 0.831469612f, 0.773010453f,
    0.707106781f, 0.634393284f, 0.555570233f, 0.471396737f,
    0.382683432f, 0.290284677f, 0.195090322f, 0.098017140f,
    0.000000000f,-0.098017140f,-0.195090322f,-0.290284677f,
   -0.382683432f,-0.471396737f,-0.555570233f,-0.634393284f,
   -0.707106781f,-0.773010453f,-0.831469612f,-0.881921264f,
   -0.923879533f,-0.956940336f,-0.980785280f,-0.995184727f};
__device__ const float TW64S[32] = {
    0.000000000f, 0.098017140f, 0.195090322f, 0.290284677f,
    0.382683432f, 0.471396737f, 0.555570233f, 0.634393284f,
    0.707106781f, 0.773010453f, 0.831469612f, 0.881921264f,
    0.923879533f, 0.956940336f, 0.980785280f, 0.995184727f,
    1.000000000f, 0.995184727f, 0.980785280f, 0.956940336f,
    0.923879533f, 0.881921264f, 0.831469612f, 0.773010453f,
    0.707106781f, 0.634393284f, 0.555570233f, 0.471396737f,
    0.382683432f, 0.290284677f, 0.195090322f, 0.098017140f};

// per-r step constants: cos/sin(pi*r/(16*DL)), r = 0..15. Compile-time folded
// (indexed only by unrolled r) -> pure literal FMAs, no recurrence chain.
template<int DL>
__device__ __forceinline__ void tw_step(int r, float& c, float& s)
{
    constexpr float c32[16] = {1.f,0.999981175f,0.999924702f,0.999830582f,0.999698819f,0.999529418f,0.999322385f,0.999077728f,0.998795456f,0.998475581f,0.998118113f,0.997723067f,0.997290457f,0.996820299f,0.996312612f,0.995767414f};
    constexpr float s32[16] = {0.f,0.006135885f,0.012271538f,0.018406730f,0.024541229f,0.030674803f,0.036807223f,0.042938257f,0.049067674f,0.055195244f,0.061320736f,0.067443920f,0.073564564f,0.079682438f,0.085797312f,0.091908956f};
    constexpr float c16[16] = {1.f,0.999924702f,0.999698819f,0.999322385f,0.998795456f,0.998118113f,0.997290457f,0.996312612f,0.995184727f,0.993906970f,0.992479535f,0.990902635f,0.989176510f,0.987301418f,0.985277642f,0.983105487f};
    constexpr float s16[16] = {0.f,0.012271538f,0.024541229f,0.036807223f,0.049067674f,0.061320736f,0.073564564f,0.085797312f,0.098017140f,0.110222207f,0.122410675f,0.134580709f,0.146730474f,0.158858143f,0.170961889f,0.183039888f};
    constexpr float c8[16]  = {1.f,0.999698819f,0.998795456f,0.997290457f,0.995184727f,0.992479535f,0.989176510f,0.985277642f,0.980785280f,0.975702130f,0.970031253f,0.963776066f,0.956940336f,0.949528181f,0.941544065f,0.932992799f};
    constexpr float s8[16]  = {0.f,0.024541229f,0.049067674f,0.073564564f,0.098017140f,0.122410675f,0.146730474f,0.170961889f,0.195090322f,0.219101240f,0.242980180f,0.266712757f,0.290284677f,0.313681740f,0.336889853f,0.359895037f};
    constexpr float c4[16]  = {1.f,0.998795456f,0.995184727f,0.989176510f,0.980785280f,0.970031253f,0.956940336f,0.941544065f,0.923879533f,0.903989293f,0.881921264f,0.857728610f,0.831469612f,0.803207531f,0.773010453f,0.740951125f};
    constexpr float s4[16]  = {0.f,0.049067674f,0.098017140f,0.146730474f,0.195090322f,0.242980180f,0.290284677f,0.336889853f,0.382683432f,0.427555093f,0.471396737f,0.514102744f,0.555570233f,0.595699304f,0.634393284f,0.671558955f};
    constexpr float c2[16]  = {1.f,0.995184727f,0.980785280f,0.956940336f,0.923879533f,0.881921264f,0.831469612f,0.773010453f,0.707106781f,0.634393284f,0.555570233f,0.471396737f,0.382683432f,0.290284677f,0.195090322f,0.098017140f};
    constexpr float s2[16]  = {0.f,0.098017140f,0.195090322f,0.290284677f,0.382683432f,0.471396737f,0.555570233f,0.634393284f,0.707106781f,0.773010453f,0.831469612f,0.881921264f,0.923879533f,0.956940336f,0.980785280f,0.995184727f};
    constexpr float c1[16]  = {1.f,0.980785280f,0.923879533f,0.831469612f,0.707106781f,0.555570233f,0.382683432f,0.195090322f,0.f,-0.195090322f,-0.382683432f,-0.555570233f,-0.707106781f,-0.831469612f,-0.923879533f,-0.980785280f};
    constexpr float s1[16]  = {0.f,0.195090322f,0.382683432f,0.555570233f,0.707106781f,0.831469612f,0.923879533f,0.980785280f,1.f,0.980785280f,0.923879533f,0.831469612f,0.707106781f,0.555570233f,0.382683432f,0.195090322f};
    if constexpr (DL == 32) { c = c32[r]; s = s32[r]; }
    else if constexpr (DL == 16) { c = c16[r]; s = s16[r]; }
    else if constexpr (DL == 8)  { c = c8[r];  s = s8[r];  }
    else if constexpr (DL == 4)  { c = c4[r];  s = s4[r];  }
    else if constexpr (DL == 2)  { c = c2[r];  s = s2[r];  }
    else                         { c = c1[r];  s = s1[r];  }
}

// ---------------- register-resident complex-1024 FFT (per wave) ----------------
// layout: point p = 16*lane + r ; forward DIF natural->bitrev, inverse DIT bitrev->natural

template<int DL>
__device__ __forceinline__ void dif_stage(float (&xr)[16], float (&xi)[16], int lane)
{
    float bcr = 1.f, bss = 0.f;
    if constexpr (DL > 1) {
        const int j = (lane & (DL - 1)) * (32 / DL);
        bcr = TW64C[j];
        bss = TW64S[j];
    }
    const float br_ = bcr, bi_ = -bss;    // forward: e^{-i pi j/32}
    const bool up = (lane & DL) != 0;
    const float sgn = up ? -1.f : 1.f;
#pragma unroll
    for (int r = 0; r < 16; ++r) {
        float sc, ss;
        tw_step<DL>(r, sc, ss);
        const float stc = sc, sti = -ss;              // W_M^r, forward
        const float twr = br_ * stc - bi_ * sti;      // tw = base * step (no chain)
        const float twi = br_ * sti + bi_ * stc;
        const float pr = __shfl_xor(xr[r], DL, 64);
        const float pi = __shfl_xor(xi[r], DL, 64);
        const float tr = fmaf(sgn, xr[r], pr);        // clear: a+b ; up: a-b
        const float ti = fmaf(sgn, xi[r], pi);
        const float mr = tr * twr - ti * twi;
        const float mi = tr * twi + ti * twr;
        xr[r] = up ? mr : tr;
        xi[r] = up ? mi : ti;
    }
}

template<int DL>
__device__ __forceinline__ void dit_stage(float (&xr)[16], float (&xi)[16], int lane)
{
    float bcr = 1.f, bss = 0.f;
    if constexpr (DL > 1) {
        const int j = (lane & (DL - 1)) * (32 / DL);
        bcr = TW64C[j];
        bss = TW64S[j];
    }
    const float br_ = bcr, bi_ = bss;     // inverse: conjugate base
    const bool up = (lane & DL) != 0;
    const float sgn = up ? -1.f : 1.f;
#pragma unroll
    for (int r = 0; r < 16; ++r) {
        float sc, ss;
        tw_step<DL>(r, sc, ss);
        const float stc = sc, sti = ss;               // conj step
        const float twr = br_ * stc - bi_ * sti;
        const float twi = br_ * sti + bi_ * stc;
        const float pr  = __shfl_xor(xr[r], DL, 64);
        const float pim = __shfl_xor(xi[r], DL, 64);
        const float vr = up ? xr[r] : pr;    // 'b' operand (gets twiddled)
        const float vi = up ? xi[r] : pim;
        const float ur = up ? pr : xr[r];    // 'a' operand
        const float ui = up ? pim : xi[r];
        const float cr_ = vr * twr - vi * twi;
        const float ci_ = vr * twi + vi * twr;
        xr[r] = fmaf(sgn, cr_, ur);          // clear: a + tw*b ; up: a - tw*b
        xi[r] = fmaf(sgn, ci_, ui);
    }
}

// forward in-register stages: M = 16, 8, 4, 2 (compile-time twiddles)
__device__ __forceinline__ void fft_inreg_fwd(float (&xr)[16], float (&xi)[16])
{
    const float R16[8] = {1.f, 0.92387953f, 0.70710678f, 0.38268343f, 0.f, -0.38268343f, -0.70710678f, -0.92387953f};
    const float I16[8] = {0.f, -0.38268343f, -0.70710678f, -0.92387953f, -1.f, -0.92387953f, -0.70710678f, -0.38268343f};
#pragma unroll
    for (int j = 0; j < 8; ++j) {
        const float ar = xr[j], ai = xi[j], br = xr[j + 8], bi = xi[j + 8];
        const float dr = ar - br, di = ai - bi;
        xr[j] = ar + br; xi[j] = ai + bi;
        xr[j + 8] = dr * R16[j] - di * I16[j];
        xi[j + 8] = dr * I16[j] + di * R16[j];
    }
    const float R8[4] = {1.f, 0.70710678f, 0.f, -0.70710678f};
    const float I8[4] = {0.f, -0.70710678f, -1.f, -0.70710678f};
#pragma unroll
    for (int b = 0; b < 16; b += 8) {
#pragma unroll
        for (int j = 0; j < 4; ++j) {
            const int i0 = b + j, i1 = i0 + 4;
            const float ar = xr[i0], ai = xi[i0], br = xr[i1], bi = xi[i1];
            const float dr = ar - br, di = ai - bi;
            xr[i0] = ar + br; xi[i0] = ai + bi;
            xr[i1] = dr * R8[j] - di * I8[j];
            xi[i1] = dr * I8[j] + di * R8[j];
        }
    }
#pragma unroll
    for (int b = 0; b < 16; b += 4) {
        {
            const float ar = xr[b], ai = xi[b], br = xr[b + 2], bi = xi[b + 2];
            xr[b] = ar + br; xi[b] = ai + bi;
            xr[b + 2] = ar - br; xi[b + 2] = ai - bi;
        }
        {   // twiddle -i: (d)*(-i) = (di, -dr)
            const float ar = xr[b + 1], ai = xi[b + 1], br = xr[b + 3], bi = xi[b + 3];
            const float dr = ar - br, di = ai - bi;
            xr[b + 1] = ar + br; xi[b + 1] = ai + bi;
            xr[b + 3] = di; xi[b + 3] = -dr;
        }
    }
#pragma unroll
    for (int b = 0; b < 16; b += 2) {
        const float ar = xr[b], ai = xi[b], br = xr[b + 1], bi = xi[b + 1];
        xr[b] = ar + br; xi[b] = ai + bi;
        xr[b + 1] = ar - br; xi[b + 1] = ai - bi;
    }
}

// inverse in-register stages: M = 2, 4, 8, 16 (DIT form, conjugate twiddles)
__device__ __forceinline__ void fft_inreg_inv(float (&xr)[16], float (&xi)[16])
{
#pragma unroll
    for (int b = 0; b < 16; b += 2) {
        const float ar = xr[b], ai = xi[b], br = xr[b + 1], bi = xi[b + 1];
        xr[b] = ar + br; xi[b] = ai + bi;
        xr[b + 1] = ar - br; xi[b + 1] = ai - bi;
    }
#pragma unroll
    for (int b = 0; b < 16; b += 4) {
        {
            const float ar = xr[b], ai = xi[b], tr = xr[b + 2], ti = xi[b + 2];
            xr[b] = ar + tr; xi[b] = ai + ti;
            xr[b + 2] = ar - tr; xi[b + 2] = ai - ti;
        }
        {   // twiddle +i: t = i*b = (-bi, br)
            const float ar = xr[b + 1], ai = xi[b + 1], br = xr[b + 3], bi = xi[b + 3];
            const float tr = -bi, ti = br;
            xr[b + 1] = ar + tr; xi[b + 1] = ai + ti;
            xr[b + 3] = ar - tr; xi[b + 3] = ai - ti;
        }
    }
    const float R8[4] = {1.f, 0.70710678f, 0.f, -0.70710678f};
    const float I8[4] = {0.f, 0.70710678f, 1.f, 0.70710678f};
#pragma unroll
    for (int b = 0; b < 16; b += 8) {
#pragma unroll
        for (int j = 0; j < 4; ++j) {
            const int i0 = b + j, i1 = i0 + 4;
            const float br = xr[i1], bi = xi[i1];
            const float tr = br * R8[j] - bi * I8[j];
            const float ti = br * I8[j] + bi * R8[j];
            const float ar = xr[i0], ai = xi[i0];
            xr[i0] = ar + tr; xi[i0] = ai + ti;
            xr[i1] = ar - tr; xi[i1] = ai - ti;
        }
    }
    const float R16[8] = {1.f, 0.92387953f, 0.70710678f, 0.38268343f, 0.f, -0.38268343f, -0.70710678f, -0.92387953f};
    const float I16[8] = {0.f, 0.38268343f, 0.70710678f, 0.92387953f, 1.f, 0.92387953f, 0.70710678f, 0.38268343f};
#pragma unroll
    for (int j = 0; j < 8; ++j) {
        const int i0 = j, i1 = j + 8;
        const float br = xr[i1], bi = xi[i1];
        const float tr = br * R16[j] - bi * I16[j];
        const float ti = br * I16[j] + bi * R16[j];
        const float ar = xr[i0], ai = xi[i0];
        xr[i0] = ar + tr; xi[i0] = ai + ti;
        xr[i1] = ar - tr; xi[i1] = ai - ti;
    }
}

__device__ __forceinline__ void fft1024_fwd(float (&xr)[16], float (&xi)[16], int lane)
{
    dif_stage<32>(xr, xi, lane);
    dif_stage<16>(xr, xi, lane);
    dif_stage<8>(xr, xi, lane);
    dif_stage<4>(xr, xi, lane);
    dif_stage<2>(xr, xi, lane);
    dif_stage<1>(xr, xi, lane);
    fft_inreg_fwd(xr, xi);
}

__device__ __forceinline__ void fft1024_inv(float (&xr)[16], float (&xi)[16], int lane)
{
    fft_inreg_inv(xr, xi);
    dit_stage<1>(xr, xi, lane);
    dit_stage<2>(xr, xi, lane);
    dit_stage<4>(xr, xi, lane);
    dit_stage<8>(xr, xi, lane);
    dit_stage<16>(xr, xi, lane);
    dit_stage<32>(xr, xi, lane);
}

// ---------------- Kernel A: FFT autocorrelation ----------------
// grid: (E/16, H, N), block = 512 (8 waves); each block: 16 series of (n,h)
__global__ __launch_bounds__(512, 1) void fftcorr_kernel(
    const float* __restrict__ q, const float* __restrict__ k,
    float* __restrict__ corr_out, float* __restrict__ ws_mean)
{
    extern __shared__ float lds[];
    float* lq = lds;
    float* lk = lds + 16 * RS;

    const int tid = threadIdx.x;
    const int n = blockIdx.z, h = blockIdx.y, e0 = blockIdx.x * 16;

    // ---- stage q,k: float4 loads (64B coalesced), scalar LDS writes into padded rows
    {
        const int eq = tid & 3;       // which float4 of the 16 e's
        const int trow = tid >> 2;    // 0..127
#pragma unroll
        for (int c = 0; c < 8; ++c) {
            const int t = c * 128 + trow;
            const size_t gbase = ((((size_t)n * L_SEQ + t) * NH + h) * NE) + e0 + 4 * eq;
            const float4 qv = *reinterpret_cast<const float4*>(q + gbase);
            const float4 kv = *reinterpret_cast<const float4*>(k + gbase);
            const int ph = physp(t);
            lq[(4 * eq + 0) * RS + ph] = qv.x;
            lq[(4 * eq + 1) * RS + ph] = qv.y;
            lq[(4 * eq + 2) * RS + ph] = qv.z;
            lq[(4 * eq + 3) * RS + ph] = qv.w;
            lk[(4 * eq + 0) * RS + ph] = kv.x;
            lk[(4 * eq + 1) * RS + ph] = kv.y;
            lk[(4 * eq + 2) * RS + ph] = kv.z;
            lk[(4 * eq + 3) * RS + ph] = kv.w;
        }
    }
    __syncthreads();

    const int lane = tid & 63;
    const int wv = tid >> 6;          // 0..7

#pragma unroll 1
    for (int s = 0; s < 2; ++s) {
        const int e = 2 * wv + s;
        const int row = e * RS + 17 * lane;   // physp(16*lane + r) = 17*lane + r
        float ar[16], ai[16];

        // ---- Q forward FFT
#pragma unroll
        for (int r = 0; r < 16; ++r) { ar[r] = lq[row + r]; ai[r] = 0.f; }
        fft1024_fwd(ar, ai, lane);

        // park Q.re in the (dead) q LDS row; keep Q.im in regs
        float qi[16];
#pragma unroll
        for (int r = 0; r < 16; ++r) { lq[row + r] = ar[r]; qi[r] = ai[r]; }

        // ---- K forward FFT
#pragma unroll
        for (int r = 0; r < 16; ++r) { ar[r] = lk[row + r]; ai[r] = 0.f; }
        fft1024_fwd(ar, ai, lane);

        // ---- S = Q * conj(K) / 1024  (elementwise in bit-reversed order)
#pragma unroll
        for (int r = 0; r < 16; ++r) {
            const float qr = lq[row + r];         // per-lane own slots, conflict-free
            const float sr = qr * ar[r] + qi[r] * ai[r];
            const float si = qi[r] * ar[r] - qr * ai[r];
            ar[r] = sr * (1.f / 1024.f);
            ai[r] = si * (1.f / 1024.f);
        }

        fft1024_inv(ar, ai, lane);            // corr (natural order, real)

#pragma unroll
        for (int r = 0; r < 16; ++r) lq[row + r] = ar[r];
    }
    __syncthreads();

    // ---- transposed coalesced writeout + per-l mean partials
    {
        const int j = tid & 15;       // e within tile
        const int lr = tid >> 4;      // 0..31
#pragma unroll 1
        for (int c = 0; c < 32; ++c) {
            const int l = c * 32 + lr;
            const float val = lq[j * RS + physp(l)];
            corr_out[((((size_t)n * L_SEQ + l) * NH + h) * NE) + e0 + j] = val;
            float sum = val;
            sum += __shfl_xor(sum, 1, 64);
            sum += __shfl_xor(sum, 2, 64);
            sum += __shfl_xor(sum, 4, 64);
            sum += __shfl_xor(sum, 8, 64);
            if (j == 0) atomicAdd(&ws_mean[n * L_SEQ + l], sum);
        }
    }
}

// ---------------- Kernel B: top-6 lags + per-n softmax ----------------
__global__ __launch_bounds__(1024) void topk_softmax_kernel(
    const float* __restrict__ ws_mean, int* __restrict__ ws_idx,
    float* __restrict__ ws_w)
{
    __shared__ float val[1024];
    __shared__ float rv[1024];
    __shared__ int   ri[1024];
    __shared__ int   sel[TOPK];
    const int tid = threadIdx.x;

    float s = 0.f;
    for (int n = 0; n < NB; ++n) s += ws_mean[n * L_SEQ + tid];
    val[tid] = s;
    __syncthreads();

    for (int kk = 0; kk < TOPK; ++kk) {
        rv[tid] = val[tid];
        ri[tid] = tid;
        __syncthreads();
        for (int off = 512; off > 0; off >>= 1) {
            if (tid < off) {
                const float a = rv[tid], b = rv[tid + off];
                const int ia = ri[tid], ib = ri[tid + off];
                if (b > a || (b == a && ib < ia)) { rv[tid] = b; ri[tid] = ib; }
            }
            __syncthreads();
        }
        if (tid == 0) { sel[kk] = ri[0]; val[ri[0]] = -1e30f; }
        __syncthreads();
    }
    if (tid < TOPK) ws_idx[tid] = sel[tid];

    if (tid < NB) {
        float wv[TOPK];
        float m = -1e30f;
        for (int kk = 0; kk < TOPK; ++kk) {
            wv[kk] = ws_mean[tid * L_SEQ + sel[kk]] * (1.f / (NH * NE));
            m = fmaxf(m, wv[kk]);
        }
        float sum = 0.f;
        for (int kk = 0; kk < TOPK; ++kk) { wv[kk] = expf(wv[kk] - m); sum += wv[kk]; }
        const float inv = 1.f / sum;
        for (int kk = 0; kk < TOPK; ++kk) ws_w[tid * 8 + kk] = wv[kk] * inv;
    }
}

// ---------------- Kernel C: lag-gather weighted sum of v ----------------
__global__ __launch_bounds__(256) void gather_kernel(
    const float* __restrict__ v, const int* __restrict__ ws_idx,
    const float* __restrict__ ws_w, float* __restrict__ out)
{
    const int n = blockIdx.y;
    const int idx4 = blockIdx.x * 256 + threadIdx.x;
    const int l = idx4 >> 7;
    const int r = idx4 & 127;
    const float* wrow = ws_w + n * 8;

    float4 acc = make_float4(0.f, 0.f, 0.f, 0.f);
#pragma unroll
    for (int kk = 0; kk < TOPK; ++kk) {
        const int t = (l + ws_idx[kk]) & (L_SEQ - 1);
        const float4 vv = *reinterpret_cast<const float4*>(
            v + (((size_t)n * L_SEQ + t) * (NH * NE)) + r * 4);
        const float wk = wrow[kk];
        acc.x = fmaf(wk, vv.x, acc.x);
        acc.y = fmaf(wk, vv.y, acc.y);
        acc.z = fmaf(wk, vv.z, acc.z);
        acc.w = fmaf(wk, vv.w, acc.w);
    }
    *reinterpret_cast<float4*>(out + ((size_t)n * L_SEQ + l) * (NH * NE) + r * 4) = acc;
}

extern "C" void kernel_launch(void* const* d_in, const int* in_sizes, int n_in,
                              void* d_out, int out_size, void* d_ws, size_t ws_size,
                              hipStream_t stream)
{
    const float* q = (const float*)d_in[0];
    const float* k = (const float*)d_in[1];
    const float* v = (const float*)d_in[2];
    float* out = (float*)d_out;
    float* corr_out = out + (size_t)NB * L_SEQ * NH * NE;

    float* ws_mean = (float*)d_ws;                              // 32*1024 f32
    int*   ws_idx  = (int*)((char*)d_ws + 131072);              // 6 ints
    float* ws_w    = (float*)((char*)d_ws + 131072 + 256);      // 32*8 f32

    hipMemsetAsync(d_ws, 0, 131072, stream);
    const size_t lds_bytes = (size_t)2 * 16 * RS * sizeof(float);   // 139,392 B
    fftcorr_kernel<<<dim3(NE / 16, NH, NB), 512, lds_bytes, stream>>>(q, k, corr_out, ws_mean);
    topk_softmax_kernel<<<1, 1024, 0, stream>>>(ws_mean, ws_idx, ws_w);
    gather_kernel<<<dim3(512, NB), 256, 0, stream>>>(v, ws_idx, ws_w, out);
}